// Round 4
// baseline (588.553 us; speedup 1.0000x reference)
//
#include <hip/hip_runtime.h>
#include <hip/hip_cooperative_groups.h>
#include <hip/hip_bf16.h>
#include <cstdint>

namespace cg = cooperative_groups;

// Problem constants
#define T_  4
#define B_  32
#define C_  384
#define HF_ 1536
#define HW_ 196
#define E_  8
#define N_  128
#define REC_CAP 16384
#define GRID_ 768
#define NTASK (N_ * 14)    // 1792 (n,h) tasks

struct Params {
  const float *x, *rw, *rb, *rg, *rbeta, *rmean, *rvar;
  const float *w1, *b1, *g1, *be1, *m1, *v1;
  const float *w2, *b2, *g2, *be2, *m2, *v2, *taus;
  float* out; float* aux_out;
  int* header;            // [0]=rec_count [1]=task counter [8..15]=f_acc [16..23]=p_acc
  float *f_acc, *p_acc;
  float* cnt; int* sel_e; float* sel_g; float* gsum; float* K;
  float *A, *Bc, *const2, *inv2v;
  int* rec;
  __hip_bfloat16* w1t;
};

__device__ __forceinline__ void acc24(uint4 u0, uint4 u1, uint4 u2, float* acc) {
  uint32_t us[12] = {u0.x, u0.y, u0.z, u0.w, u1.x, u1.y, u1.z, u1.w,
                     u2.x, u2.y, u2.z, u2.w};
  #pragma unroll
  for (int d = 0; d < 12; ++d) {
    acc[2 * d]     += __uint_as_float(us[d] << 16);
    acc[2 * d + 1] += __uint_as_float(us[d] & 0xffff0000u);
  }
}

// phases: 1=prep+lif+transpose  2=router  3=main  4=apply
// grid.sync() only executes when pmin<pmax (cooperative multi-phase run).
__global__ __launch_bounds__(256, 3) void k_mega(Params p, int pmin, int pmax) {
  __shared__ __align__(16) char smem[28160];
  __shared__ int s_i1, s_i2, s_task;
  __shared__ float s_g1, s_g2;
  int bid = blockIdx.x, tid = threadIdx.x;
  int lane = tid & 63, wave = tid >> 6;
  bool multi = pmin < pmax;

  // ===================== Phase 1: prep + LIF + transpose =====================
  if (pmin <= 1 && 1 <= pmax) {
    // ---- prep (one pass; only low blocks hit it) ----
    {
      int idx = bid * 256 + tid;
      if (idx < 64) p.header[idx] = 0;
      if (idx < E_ * HF_) {
        int e = idx / HF_;
        float inv = p.g1[idx] / sqrtf(p.v1[idx] + 1e-5f);
        float sh  = p.be1[idx] - p.m1[idx] * inv;
        p.A[idx]  = inv;
        p.Bc[idx] = inv * p.b1[idx] + sh - p.taus[e];
      }
      if (idx < E_ * C_) {
        float inv = p.g2[idx] / sqrtf(p.v2[idx] + 1e-5f);
        p.const2[idx] = p.b2[idx] * inv + (p.be2[idx] - p.m2[idx] * inv);
        p.inv2v[idx]  = inv;
      }
    }
    // ---- LIF: one wave per (b,c); 16 independent loads; packed shfl reduce ----
    const float* __restrict__ xr = p.x;
    for (int bc = bid * 4 + wave; bc < B_ * C_; bc += GRID_ * 4) {
      size_t base = (size_t)bc * HW_;
      float v0 = 0.f, v1 = 0.f, v2 = 0.f, v3 = 0.f;
      int pk = 0;
      #pragma unroll
      for (int t = 0; t < T_; ++t) {
        const float* xt = xr + (size_t)t * (B_ * C_ * HW_) + base;
        float a0 = xt[lane];
        float a1 = xt[lane + 64];
        float a2 = xt[lane + 128];
        float a3 = (lane < 4) ? xt[192 + lane] : -1e30f;
        int c = 0;
        v0 = v0 + (a0 - v0) * 0.5f;
        if (v0 - 1.0f >= 0.0f) { c++; v0 = 0.f; }
        v1 = v1 + (a1 - v1) * 0.5f;
        if (v1 - 1.0f >= 0.0f) { c++; v1 = 0.f; }
        v2 = v2 + (a2 - v2) * 0.5f;
        if (v2 - 1.0f >= 0.0f) { c++; v2 = 0.f; }
        v3 = v3 + (a3 - v3) * 0.5f;
        if (v3 - 1.0f >= 0.0f) { c++; v3 = 0.f; }
        pk += c << (8 * t);
      }
      #pragma unroll
      for (int off = 1; off < 64; off <<= 1) pk += __shfl_xor(pk, off, 64);
      if (lane == 0) {
        #pragma unroll
        for (int t = 0; t < T_; ++t)
          p.cnt[(size_t)t * (B_ * C_) + bc] = (float)((pk >> (8 * t)) & 255);
      }
    }
    // ---- transpose w1 -> bf16 w1t (3 tiles per block, uniform) ----
    float (*tile)[33] = (float(*)[33])smem;
    for (int tl = bid; tl < E_ * 288; tl += GRID_) {
      int e = tl / 288, r2 = tl % 288;
      int c0 = (r2 / 24) * 32, o0 = (r2 % 24) * 64;
      int cl = tid & 31, olb = tid >> 5;
      __syncthreads();
      #pragma unroll
      for (int it = 0; it < 8; ++it) {
        int ol = olb + it * 8;
        tile[ol & 63][cl] = p.w1[(size_t)(e * HF_ + o0 + ol) * C_ + c0 + cl];
      }
      __syncthreads();
      int ol2 = tid & 63, clb = tid >> 6;
      #pragma unroll
      for (int it = 0; it < 8; ++it) {
        int cl2 = clb + it * 4;
        p.w1t[(size_t)(e * C_ + c0 + cl2) * HF_ + o0 + ol2] =
            __float2bfloat16(tile[ol2][cl2]);
      }
    }
  }
  if (multi) cg::this_grid().sync();

  // ===================== Phase 2: router =====================
  if (pmin <= 2 && 2 <= pmax && bid < N_) {
    int n = bid;
    float* sc   = (float*)smem;        // 384
    float* part = sc + C_;             // 256
    float* lg   = part + 256;          // 8
    for (int c = tid; c < C_; c += 256) sc[c] = p.cnt[(size_t)n * C_ + c];
    __syncthreads();
    {
      int e = tid >> 5, sub = tid & 31;
      float d = 0.f;
      for (int c = sub; c < C_; c += 32) d += p.rw[e * C_ + c] * sc[c];
      part[tid] = d;
    }
    __syncthreads();
    if (tid < E_) {
      float dot = 0.f;
      #pragma unroll
      for (int j = 0; j < 32; ++j) dot += part[tid * 32 + j];
      float inv = p.rg[tid] / sqrtf(p.rvar[tid] + 1e-5f);
      lg[tid] = (dot * (1.0f / HW_) + p.rb[tid]) * inv +
                (p.rbeta[tid] - p.rmean[tid] * inv);
    }
    __syncthreads();
    if (tid == 0) {
      float m = lg[0];
      for (int e = 1; e < E_; ++e) m = fmaxf(m, lg[e]);
      float pr[E_]; float s = 0.f;
      for (int e = 0; e < E_; ++e) { pr[e] = expf(lg[e] - m); s += pr[e]; }
      float invs = 1.0f / s;
      for (int e = 0; e < E_; ++e) pr[e] *= invs;
      int i1 = 0;
      for (int e = 1; e < E_; ++e) if (pr[e] > pr[i1]) i1 = e;
      int i2 = (i1 == 0) ? 1 : 0;
      for (int e = 0; e < E_; ++e) if (e != i1 && pr[e] > pr[i2]) i2 = e;
      float w = pr[i1] + pr[i2];
      float ga = pr[i1] / w, gb = pr[i2] / w;
      p.sel_e[2 * n] = i1; p.sel_e[2 * n + 1] = i2;
      p.sel_g[2 * n] = ga; p.sel_g[2 * n + 1] = gb;
      p.gsum[n] = ga + gb;
      s_i1 = i1; s_i2 = i2; s_g1 = ga; s_g2 = gb;
      atomicAdd(&p.f_acc[i1], 1.0f);
      atomicAdd(&p.f_acc[i2], 1.0f);
      for (int e = 0; e < E_; ++e) atomicAdd(&p.p_acc[e], pr[e]);
    }
    __syncthreads();
    int i1 = s_i1, i2 = s_i2; float ga = s_g1, gb = s_g2;
    for (int c = tid; c < C_; c += 256)
      p.K[(size_t)n * C_ + c] =
          ga * p.const2[i1 * C_ + c] + gb * p.const2[i2 * C_ + c];
  }
  if (multi) cg::this_grid().sync();

  // ===================== Phase 3: main (work-stealing) =====================
  if (pmin <= 3 && 3 <= pmax) {
    float* xs = (float*)smem;                       // 14*385 floats = 21560 B
    int* sl = (int*)(smem + 21560) + wave * C_;     // wave-private spike list
    unsigned long long lmask = (1ull << lane) - 1ull;
    while (true) {
      __syncthreads();
      if (tid == 0) s_task = atomicAdd(&p.header[1], 1);
      __syncthreads();
      int task = s_task;
      if (task >= NTASK) break;
      int n = task / 14, h = task - n * 14;

      // stage x row h (float2): xs[w*385 + c]
      for (int idx = tid; idx < C_ * 7; idx += 256) {
        int c = idx / 7, wp = idx - c * 7;
        float2 v = *(const float2*)(p.x + ((size_t)(n * C_ + c) * 14 + h) * 14 + 2 * wp);
        xs[(2 * wp) * 385 + c]     = v.x;
        xs[(2 * wp + 1) * 385 + c] = v.y;
      }
      __syncthreads();

      for (int t = wave; t < 28; t += 4) {
        int k = t / 14, w = t - k * 14;
        int pair = 2 * n + k;
        int e = p.sel_e[pair];
        float tau = p.taus[e];
        const uint4* wb = (const uint4*)(p.w1t + (size_t)e * C_ * HF_);
        const float4* Af = (const float4*)(p.A + e * HF_) + lane * 6;
        const float4* Bf = (const float4*)(p.Bc + e * HF_) + lane * 6;

        int nnz = 0;
        #pragma unroll
        for (int cb = 0; cb < 6; ++cb) {
          int c = cb * 64 + lane;
          bool sp = (xs[w * 385 + c] / tau - 1.0f >= 0.0f);
          unsigned long long m = __ballot(sp);
          if (sp) sl[nnz + __popcll(m & lmask)] = c;
          nnz += __popcll(m);
        }
        __asm__ volatile("s_waitcnt lgkmcnt(0)" ::: "memory");

        float acc[24];
        #pragma unroll
        for (int q = 0; q < 24; ++q) acc[q] = 0.f;

        int j = 0;
        for (; j + 4 <= nnz; j += 4) {           // 12 dwordx4 in flight
          const uint4* r0 = wb + sl[j + 0] * 192 + lane * 3;
          const uint4* r1 = wb + sl[j + 1] * 192 + lane * 3;
          const uint4* r2 = wb + sl[j + 2] * 192 + lane * 3;
          const uint4* r3 = wb + sl[j + 3] * 192 + lane * 3;
          uint4 a0 = r0[0], a1 = r0[1], a2 = r0[2];
          uint4 b0 = r1[0], b1 = r1[1], b2 = r1[2];
          uint4 c0 = r2[0], c1 = r2[1], c2 = r2[2];
          uint4 d0 = r3[0], d1 = r3[1], d2 = r3[2];
          acc24(a0, a1, a2, acc);
          acc24(b0, b1, b2, acc);
          acc24(c0, c1, c2, acc);
          acc24(d0, d1, d2, acc);
        }
        for (; j < nnz; ++j) {
          const uint4* r0 = wb + sl[j] * 192 + lane * 3;
          uint4 a0 = r0[0], a1 = r0[1], a2 = r0[2];
          acc24(a0, a1, a2, acc);
        }

        #pragma unroll
        for (int q4 = 0; q4 < 6; ++q4) {
          float4 Av = Af[q4];
          float4 Bv = Bf[q4];
          float a0 = Av.x * acc[q4 * 4 + 0] + Bv.x;
          float a1 = Av.y * acc[q4 * 4 + 1] + Bv.y;
          float a2 = Av.z * acc[q4 * 4 + 2] + Bv.z;
          float a3 = Av.w * acc[q4 * 4 + 3] + Bv.w;
          #pragma unroll
          for (int qi = 0; qi < 4; ++qi) {
            float av = (qi == 0) ? a0 : (qi == 1) ? a1 : (qi == 2) ? a2 : a3;
            if (av >= 0.0f) {                    // layer-2 spike (rare)
              int ridx = atomicAdd(&p.header[0], 1);
              if (ridx < REC_CAP) {
                p.rec[ridx * 3 + 0] = pair;
                p.rec[ridx * 3 + 1] = h * 14 + w;
                p.rec[ridx * 3 + 2] = lane * 24 + q4 * 4 + qi;
              }
            }
          }
        }
      }
      __syncthreads();   // all waves done reading xs before next combine/stage

      // fused combine: out = gsum*x + K (float2)
      float g = p.gsum[n];
      const float* Kn = p.K + (size_t)n * C_;
      for (int idx = tid; idx < C_ * 7; idx += 256) {
        int c = idx / 7, wp = idx - c * 7;
        float kc = Kn[c];
        float2 v;
        v.x = g * xs[(2 * wp) * 385 + c] + kc;
        v.y = g * xs[(2 * wp + 1) * 385 + c] + kc;
        *(float2*)(p.out + ((size_t)(n * C_ + c) * 14 + h) * 14 + 2 * wp) = v;
      }
    }
  }
  if (multi) cg::this_grid().sync();

  // ===================== Phase 4: apply records + aux =====================
  if (pmin <= 4 && 4 <= pmax) {
    int nrec = p.header[0];
    if (nrec > REC_CAP) nrec = REC_CAP;
    for (int r = bid; r < nrec; r += GRID_) {
      int pair = p.rec[r * 3], pos = p.rec[r * 3 + 1], o = p.rec[r * 3 + 2];
      int n = pair >> 1;
      int e = p.sel_e[pair];
      float g = p.sel_g[pair];
      for (int c = tid; c < C_; c += 256) {
        float wv = p.w2[(size_t)(e * C_ + c) * HF_ + o];
        atomicAdd(&p.out[(size_t)(n * C_ + c) * HW_ + pos],
                  g * p.inv2v[e * C_ + c] * wv);
      }
    }
    if (bid == 0 && tid == 0) {
      float s = 0.f;
      for (int e = 0; e < E_; ++e)
        s += (p.f_acc[e] * (1.0f / N_)) * (p.p_acc[e] * (1.0f / N_));
      *p.aux_out = 0.01f * E_ * s;
    }
  }
}

extern "C" void kernel_launch(void* const* d_in, const int* in_sizes, int n_in,
                              void* d_out, int out_size, void* d_ws, size_t ws_size,
                              hipStream_t stream) {
  Params prm;
  prm.x     = (const float*)d_in[0];
  prm.rw    = (const float*)d_in[1];
  prm.rb    = (const float*)d_in[2];
  prm.rg    = (const float*)d_in[3];
  prm.rbeta = (const float*)d_in[4];
  prm.rmean = (const float*)d_in[5];
  prm.rvar  = (const float*)d_in[6];
  prm.w1    = (const float*)d_in[7];
  prm.b1    = (const float*)d_in[8];
  prm.g1    = (const float*)d_in[9];
  prm.be1   = (const float*)d_in[10];
  prm.m1    = (const float*)d_in[11];
  prm.v1    = (const float*)d_in[12];
  prm.w2    = (const float*)d_in[13];
  prm.b2    = (const float*)d_in[14];
  prm.g2    = (const float*)d_in[15];
  prm.be2   = (const float*)d_in[16];
  prm.m2    = (const float*)d_in[17];
  prm.v2    = (const float*)d_in[18];
  prm.taus  = (const float*)d_in[19];
  prm.out   = (float*)d_out;
  prm.aux_out = (float*)d_out + (out_size - 1);

  char* ws = (char*)d_ws;
  prm.header = (int*)ws;
  prm.f_acc  = (float*)ws + 8;
  prm.p_acc  = (float*)ws + 16;
  prm.cnt    = (float*)(ws + 256);
  prm.sel_e  = (int*)(ws + 196864);
  prm.sel_g  = (float*)(ws + 197888);
  prm.gsum   = (float*)(ws + 198912);
  prm.K      = (float*)(ws + 199424);
  prm.A      = (float*)(ws + 396032);
  prm.Bc     = (float*)(ws + 445184);
  prm.const2 = (float*)(ws + 494336);
  prm.inv2v  = (float*)(ws + 506624);
  prm.rec    = (int*)(ws + 518912);
  prm.w1t    = (__hip_bfloat16*)(ws + 715520);

  int lo = 1, hi = 4;
  void* args[] = {&prm, &lo, &hi};
  hipError_t err = hipLaunchCooperativeKernel((const void*)k_mega,
                                              dim3(GRID_), dim3(256),
                                              args, 0, stream);
  if (err != hipSuccess) {
    // fallback: 4 plain launches, phase-by-phase (no grid.sync executed)
    for (int ph = 1; ph <= 4; ++ph) {
      k_mega<<<GRID_, 256, 0, stream>>>(prm, ph, ph);
    }
  }
}